// Round 3
// baseline (232.541 us; speedup 1.0000x reference)
//
#include <hip/hip_runtime.h>
#include <math.h>

#define NN 32768
#define EN 1048576
#define NBIN 256          // coarse bins: bin = rcv >> 7 (128 receivers per bin)
#define BINCAP 8192       // slots per coarse bin (avg 4096, +many sigma)
#define TILE 4096         // edges per bin_k block

// C = 1/sqrt(E[gelu(z)^2]) , E = 1/3 + 1/(2*pi*sqrt(3))
#define C_GELU_F 1.5335262f

// ---------------- pass A: coarse-bin edges, coalesced writes ----------------
// word = (rcv << 15) | snd  (30 bits); bin = word >> 22.
__global__ __launch_bounds__(256) void bin_k(const int* __restrict__ snd,
                                             const int* __restrict__ rcv,
                                             int* __restrict__ bin_cur,
                                             unsigned* __restrict__ binbuf) {
    __shared__ unsigned cnt[NBIN];
    __shared__ unsigned excl[NBIN];
    __shared__ unsigned cur2[NBIN];
    __shared__ unsigned gbase[NBIN];
    __shared__ unsigned stage[TILE];
    int t = threadIdx.x;
    int tile = blockIdx.x * TILE;
    cnt[t] = 0; cur2[t] = 0;
    __syncthreads();

    unsigned w[TILE / 256];
#pragma unroll
    for (int i = 0; i < TILE / 256; ++i) {
        int e = tile + i * 256 + t;
        unsigned r = (unsigned)rcv[e], s = (unsigned)snd[e];
        w[i] = (r << 15) | s;
        atomicAdd(&cnt[w[i] >> 22], 1u);
    }
    __syncthreads();

    // inclusive Kogge-Stone over 256 counters -> excl (exclusive)
    unsigned my = cnt[t];
    excl[t] = my;
    __syncthreads();
    for (int d = 1; d < NBIN; d <<= 1) {
        unsigned v = (t >= d) ? excl[t - d] : 0u;
        __syncthreads();
        excl[t] += v;
        __syncthreads();
    }
    unsigned myexcl = excl[t] - my;
    gbase[t] = atomicAdd((unsigned*)&bin_cur[t], my);
    __syncthreads();
    excl[t] = myexcl;
    __syncthreads();

#pragma unroll
    for (int i = 0; i < TILE / 256; ++i) {
        unsigned b = w[i] >> 22;
        unsigned p = excl[b] + atomicAdd(&cur2[b], 1u);
        stage[p] = w[i];
    }
    __syncthreads();

    for (int p = t; p < TILE; p += 256) {
        unsigned ww = stage[p];
        unsigned b = ww >> 22;
        unsigned idx = gbase[b] + ((unsigned)p - excl[b]);
        if (idx < BINCAP) binbuf[b * BINCAP + idx] = ww;
    }
}

// ---------------- scan over bins -> global CSR base per bin -----------------
__global__ __launch_bounds__(256) void scan_k(const int* __restrict__ bin_cur,
                                              int* __restrict__ bin_start) {
    __shared__ unsigned sc[NBIN];
    int t = threadIdx.x;
    unsigned my = (unsigned)bin_cur[t];
    sc[t] = my;
    __syncthreads();
    for (int d = 1; d < NBIN; d <<= 1) {
        unsigned v = (t >= d) ? sc[t - d] : 0u;
        __syncthreads();
        sc[t] += v;
        __syncthreads();
    }
    bin_start[t] = (int)(sc[t] - my);
}

// ---------------- pass B: per-bin counting sort -> CSR ----------------------
__global__ __launch_bounds__(256) void csr_k(const int* __restrict__ bin_cur,
                                             const int* __restrict__ bin_start,
                                             const unsigned* __restrict__ binbuf,
                                             int* __restrict__ row_ptr,
                                             int* __restrict__ edge_csr) {
    __shared__ unsigned cnt[128];
    __shared__ unsigned excl[128];
    __shared__ unsigned cur2[128];
    int b = blockIdx.x;
    int t = threadIdx.x;
    int M = bin_cur[b]; M = M > BINCAP ? BINCAP : M;
    int base = bin_start[b];
    if (t < 128) { cnt[t] = 0; cur2[t] = 0; }
    __syncthreads();

    const unsigned* bb = binbuf + b * BINCAP;
    for (int i = t; i < M; i += 256)
        atomicAdd(&cnt[(bb[i] >> 15) & 127], 1u);
    __syncthreads();

    if (t < 128) excl[t] = cnt[t];
    __syncthreads();
    for (int d = 1; d < 128; d <<= 1) {
        unsigned v = (t >= d && t < 128) ? excl[t - d] : 0u;
        __syncthreads();
        if (t < 128) excl[t] += v;
        __syncthreads();
    }
    if (t < 128) {
        unsigned e = excl[t] - cnt[t];
        excl[t] = e;
        row_ptr[(b << 7) + t] = base + (int)e;
        if (b == NBIN - 1 && t == 127) row_ptr[NN] = base + (int)(e + cnt[127]);
    }
    __syncthreads();

    for (int i = t; i < M; i += 256) {
        unsigned ww = bb[i];
        unsigned r7 = (ww >> 15) & 127;
        unsigned dst = excl[r7] + atomicAdd(&cur2[r7], 1u);
        edge_csr[base + dst] = (int)(ww & 0x7FFF);
    }
}

// ---------------- pack positions into float4 for 16B loads ------------------
__global__ __launch_bounds__(256) void pos_k(const float* __restrict__ pos,
                                             float4* __restrict__ posw) {
    int n = blockIdx.x * 256 + threadIdx.x;
    posw[n] = make_float4(pos[3*n], pos[3*n+1], pos[3*n+2], 0.f);
}

// ---------------- fused aggregate + node update ------------------------------
// Phase 1: 16 lanes/node, lane u accumulates agg[n,u,0:16] in registers.
// Phase 2: 16x16 in-LDS transpose per node (stride-17 pad -> <=2-way banks).
// Phase 3: thread (n,j) does linear_pre -> gelu(0e) -> linear_post -> shortcut.
#define TSTRIDE 17
#define NSTRIDE (16 * TSTRIDE)   // 272 floats per node

__global__ __launch_bounds__(256) void fused_k(const float* __restrict__ x,
                                               const float4* __restrict__ posw,
                                               const int* __restrict__ row_ptr,
                                               const int* __restrict__ edge_csr,
                                               const float* __restrict__ Wpre,
                                               const float* __restrict__ Wpost,
                                               const float* __restrict__ Wsc,
                                               float* __restrict__ out) {
    __shared__ float sPre[4*516];
    __shared__ float sPost[4*1028];
    __shared__ float sSc[512];
    __shared__ float sT[16 * NSTRIDE];   // 16 nodes x (16u x 16j), padded

    int t = threadIdx.x;
    for (int idx = t; idx < 2048; idx += 256)
        sPre[(idx >> 9)*516 + (idx & 511)] = Wpre[idx];
    for (int idx = t; idx < 4096; idx += 256)
        sPost[(idx >> 10)*1028 + (idx & 1023)] = Wpost[idx];
    sSc[t] = Wsc[t];
    sSc[t + 256] = Wsc[t + 256];

    // ---- phase 1: gather + SH accumulate ----
    int nl = t >> 4;                       // local node 0..15
    int n  = blockIdx.x * 16 + nl;
    int u  = t & 15;
    int beg = row_ptr[n], end = row_ptr[n + 1];
    int cnt = end - beg;
    float4 rp = posw[n];
    float acc[16];
#pragma unroll
    for (int j = 0; j < 16; ++j) acc[j] = 0.f;

    const float s3   = 1.7320508075688772f;
    const float s5   = 2.2360679774997896f;
    const float s15  = 3.8729833462074170f;
    const float s7   = 2.6457513110645907f;
    const float s105 = 10.246950765959598f;
    const float s35_8 = 2.0916500663351889f;
    const float s21_8 = 1.6201851746019651f;

    // software pipeline: edge index 2 ahead, payload 1 ahead (clamped, no branch)
    int cl = cnt > 0 ? cnt - 1 : 0;
    int sA = edge_csr[beg];                 // edge k
    int sB = edge_csr[beg + (1 < cl ? 1 : cl)];   // edge k+1
    float4 spA = posw[sA];
    float  xvA = x[(sA << 4) + u];

    for (int k = 0; k < cnt; ++k) {
        int    s  = sA;
        float4 sp = spA;
        float  sv = xvA;
        sA = sB;
        int k2 = k + 2; k2 = k2 < cl ? k2 : cl;
        sB = edge_csr[beg + k2];
        spA = posw[sA];
        xvA = x[(sA << 4) + u];

        float vx = rp.x - sp.x, vy = rp.y - sp.y, vz = rp.z - sp.z;
        float n2 = vx*vx + vy*vy + vz*vz;
        float inv;
        if (n2 > 0.f) {
            inv = rsqrtf(n2);
            inv = inv * (1.5f - 0.5f * n2 * inv * inv);   // Newton: ~exact f32
        } else inv = 0.f;
        float X = vx*inv, Y = vy*inv, Z = vz*inv;
        float XX = X*X, YY = Y*Y, ZZ = Z*Z;

        acc[0]  += sv;
        acc[1]  += sv * (s3*X);
        acc[2]  += sv * (s3*Y);
        acc[3]  += sv * (s3*Z);
        acc[4]  += sv * (s15*X*Y);
        acc[5]  += sv * (s15*Y*Z);
        acc[6]  += sv * (0.5f*s5*(3.f*ZZ - 1.f));
        acc[7]  += sv * (s15*X*Z);
        acc[8]  += sv * (0.5f*s15*(XX - YY));
        acc[9]  += sv * (s35_8*Y*(3.f*XX - YY));
        acc[10] += sv * (s105*X*Y*Z);
        acc[11] += sv * (s21_8*Y*(5.f*ZZ - 1.f));
        acc[12] += sv * (0.5f*s7*Z*(5.f*ZZ - 3.f));
        acc[13] += sv * (s21_8*X*(5.f*ZZ - 1.f));
        acc[14] += sv * (0.5f*s105*Z*(XX - YY));
        acc[15] += sv * (s35_8*X*(XX - 3.f*YY));
    }

    // ---- phase 2: transpose through LDS ----
    float* tp = sT + nl * NSTRIDE + u * TSTRIDE;
#pragma unroll
    for (int j = 0; j < 16; ++j) tp[j] = acc[j];
    __syncthreads();

    // ---- phase 3: per-(n,j) node update ----
    int j = t & 15;
    int l, i, offl, deg;
    if (j == 0)      { l = 0; i = 0;     offl = 0;   deg = 1; }
    else if (j < 4)  { l = 1; i = j - 1; offl = 32;  deg = 3; }
    else if (j < 9)  { l = 2; i = j - 4; offl = 128; deg = 5; }
    else             { l = 3; i = j - 9; offl = 288; deg = 7; }

    const float c1 = 0.0078125f;            // (1/DENOM) * inv_in
    const float c2 = 0.17677669529663687f;  // 1/sqrt(32)

    const float* ap = sT + nl * NSTRIDE + j;
    float p[32];
#pragma unroll
    for (int v = 0; v < 32; ++v) p[v] = 0.f;
    const float* wp = sPre + l * 516;
#pragma unroll
    for (int uu = 0; uu < 16; ++uu) {
        float a = ap[uu * TSTRIDE];
        const float4* w4 = (const float4*)(wp + (uu << 5));
#pragma unroll
        for (int vq = 0; vq < 8; ++vq) {
            float4 w = w4[vq];
            p[4*vq+0] += a * w.x;
            p[4*vq+1] += a * w.y;
            p[4*vq+2] += a * w.z;
            p[4*vq+3] += a * w.w;
        }
    }
#pragma unroll
    for (int v = 0; v < 32; ++v) p[v] *= c1;

    if (j == 0) {
#pragma unroll
        for (int v = 0; v < 32; ++v) {
            float pv = p[v];
            p[v] = C_GELU_F * 0.5f * pv * (1.f + erff(pv * 0.7071067811865476f));
        }
    }

    float q[32];
#pragma unroll
    for (int w = 0; w < 32; ++w) q[w] = 0.f;
    const float* wq = sPost + l * 1028;
#pragma unroll
    for (int v = 0; v < 32; ++v) {
        float pv = p[v];
        const float4* w4 = (const float4*)(wq + (v << 5));
#pragma unroll
        for (int wd = 0; wd < 8; ++wd) {
            float4 w = w4[wd];
            q[4*wd+0] += pv * w.x;
            q[4*wd+1] += pv * w.y;
            q[4*wd+2] += pv * w.z;
            q[4*wd+3] += pv * w.w;
        }
    }
#pragma unroll
    for (int w = 0; w < 32; ++w) q[w] *= c2;

    if (j == 0) {   // shortcut: (x @ Wsc) * 1/4, only the 0e path
        const float* xp = x + (n << 4);
#pragma unroll
        for (int uu = 0; uu < 16; ++uu) {
            float xv = 0.25f * xp[uu];
            const float4* w4 = (const float4*)(sSc + (uu << 5));
#pragma unroll
            for (int wd = 0; wd < 8; ++wd) {
                float4 w = w4[wd];
                q[4*wd+0] += xv * w.x;
                q[4*wd+1] += xv * w.y;
                q[4*wd+2] += xv * w.z;
                q[4*wd+3] += xv * w.w;
            }
        }
    }

    float* op = out + (n << 9) + offl + i;
#pragma unroll
    for (int w = 0; w < 32; ++w) op[w * deg] = q[w];
}

extern "C" void kernel_launch(void* const* d_in, const int* in_sizes, int n_in,
                              void* d_out, int out_size, void* d_ws, size_t ws_size,
                              hipStream_t stream) {
    const float* x     = (const float*)d_in[0];
    const float* pos   = (const float*)d_in[1];
    const float* Wpre  = (const float*)d_in[2];
    const float* Wpost = (const float*)d_in[3];
    const float* Wsc   = (const float*)d_in[4];
    const int*   snd   = (const int*)d_in[5];
    const int*   rcv   = (const int*)d_in[6];
    float* out = (float*)d_out;

    char* ws = (char*)d_ws;
    int*      bin_cur   = (int*)(ws);                    // 1 KiB
    int*      bin_start = (int*)(ws + 1024);             // 1 KiB
    int*      row_ptr   = (int*)(ws + 2048);             // 128 KiB + 4
    float4*   posw      = (float4*)(ws + 0x30000);       // 512 KiB
    int*      edge_csr  = (int*)(ws + 0xB0000);          // 4 MiB
    unsigned* binbuf    = (unsigned*)(ws + 0x500000);    // 8 MiB

    hipMemsetAsync(bin_cur, 0, NBIN * sizeof(int), stream);
    bin_k<<<EN / TILE, 256, 0, stream>>>(snd, rcv, bin_cur, binbuf);
    scan_k<<<1, 256, 0, stream>>>(bin_cur, bin_start);
    csr_k<<<NBIN, 256, 0, stream>>>(bin_cur, bin_start, binbuf, row_ptr, edge_csr);
    pos_k<<<NN / 256, 256, 0, stream>>>(pos, posw);
    fused_k<<<NN / 16, 256, 0, stream>>>(x, posw, row_ptr, edge_csr,
                                         Wpre, Wpost, Wsc, out);
}

// Round 4
// 197.863 us; speedup vs baseline: 1.1753x; 1.1753x over previous
//
#include <hip/hip_runtime.h>
#include <math.h>

#define NN 32768
#define EN 1048576
#define NBIN 256          // coarse bins: bin = rcv >> 7 (128 receivers per bin)
#define BINCAP 8192       // slots per coarse bin (avg 4096, +many sigma)
#define TILE 4096         // edges per bin_k block

// C = 1/sqrt(E[gelu(z)^2]) , E = 1/3 + 1/(2*pi*sqrt(3))
#define C_GELU_F 1.5335262f

// ---------------- pass A: coarse-bin edges, coalesced writes ----------------
// word = (rcv << 15) | snd  (30 bits); bin = word >> 22.
__global__ __launch_bounds__(512) void bin_k(const int* __restrict__ snd,
                                             const int* __restrict__ rcv,
                                             int* __restrict__ bin_cur,
                                             unsigned* __restrict__ binbuf) {
    __shared__ unsigned cnt[NBIN];
    __shared__ unsigned excl[NBIN];
    __shared__ unsigned cur2[NBIN];
    __shared__ unsigned gbase[NBIN];
    __shared__ unsigned stage[TILE];
    int t = threadIdx.x;
    int tile = blockIdx.x * TILE;
    if (t < NBIN) { cnt[t] = 0; cur2[t] = 0; }
    __syncthreads();

    unsigned w[TILE / 512];
#pragma unroll
    for (int i = 0; i < TILE / 512; ++i) {
        int e = tile + i * 512 + t;
        unsigned r = (unsigned)rcv[e], s = (unsigned)snd[e];
        w[i] = (r << 15) | s;
        atomicAdd(&cnt[w[i] >> 22], 1u);
    }
    __syncthreads();

    // Kogge-Stone over 256 counters -> exclusive scan (barriers unconditional)
    unsigned my = (t < NBIN) ? cnt[t] : 0u;
    if (t < NBIN) excl[t] = my;
    __syncthreads();
    for (int d = 1; d < NBIN; d <<= 1) {
        unsigned v = (t < NBIN && t >= d) ? excl[t - d] : 0u;
        __syncthreads();
        if (t < NBIN) excl[t] += v;
        __syncthreads();
    }
    if (t < NBIN) {
        unsigned myexcl = excl[t] - my;
        gbase[t] = atomicAdd((unsigned*)&bin_cur[t], my);
        excl[t] = myexcl;
    }
    __syncthreads();

#pragma unroll
    for (int i = 0; i < TILE / 512; ++i) {
        unsigned b = w[i] >> 22;
        unsigned p = excl[b] + atomicAdd(&cur2[b], 1u);
        stage[p] = w[i];
    }
    __syncthreads();

    for (int p = t; p < TILE; p += 512) {
        unsigned ww = stage[p];
        unsigned b = ww >> 22;
        unsigned idx = gbase[b] + ((unsigned)p - excl[b]);
        if (idx < BINCAP) binbuf[b * BINCAP + idx] = ww;
    }
}

// ---------------- scan over bins -> global CSR base per bin -----------------
__global__ __launch_bounds__(256) void scan_k(const int* __restrict__ bin_cur,
                                              int* __restrict__ bin_start) {
    __shared__ unsigned sc[NBIN];
    int t = threadIdx.x;
    unsigned my = (unsigned)bin_cur[t];
    sc[t] = my;
    __syncthreads();
    for (int d = 1; d < NBIN; d <<= 1) {
        unsigned v = (t >= d) ? sc[t - d] : 0u;
        __syncthreads();
        sc[t] += v;
        __syncthreads();
    }
    bin_start[t] = (int)(sc[t] - my);
}

// ---------------- pass B: per-bin counting sort -> CSR ----------------------
__global__ __launch_bounds__(1024) void csr_k(const int* __restrict__ bin_cur,
                                              const int* __restrict__ bin_start,
                                              const unsigned* __restrict__ binbuf,
                                              int* __restrict__ row_ptr,
                                              int* __restrict__ edge_csr) {
    __shared__ unsigned cnt[128];
    __shared__ unsigned excl[128];
    __shared__ unsigned cur2[128];
    int b = blockIdx.x;
    int t = threadIdx.x;
    int M = bin_cur[b]; M = M > BINCAP ? BINCAP : M;
    int base = bin_start[b];
    if (t < 128) { cnt[t] = 0; cur2[t] = 0; }
    __syncthreads();

    const unsigned* bb = binbuf + b * BINCAP;
    for (int i = t; i < M; i += 1024)
        atomicAdd(&cnt[(bb[i] >> 15) & 127], 1u);
    __syncthreads();

    if (t < 128) excl[t] = cnt[t];
    __syncthreads();
    for (int d = 1; d < 128; d <<= 1) {
        unsigned v = (t >= d && t < 128) ? excl[t - d] : 0u;
        __syncthreads();
        if (t < 128) excl[t] += v;
        __syncthreads();
    }
    if (t < 128) {
        unsigned e = excl[t] - cnt[t];
        excl[t] = e;
        row_ptr[(b << 7) + t] = base + (int)e;
        if (b == NBIN - 1 && t == 127) row_ptr[NN] = base + (int)(e + cnt[127]);
    }
    __syncthreads();

    for (int i = t; i < M; i += 1024) {
        unsigned ww = bb[i];
        unsigned r7 = (ww >> 15) & 127;
        unsigned dst = excl[r7] + atomicAdd(&cur2[r7], 1u);
        edge_csr[base + dst] = (int)(ww & 0x7FFF);
    }
}

// ---------------- pack positions into float4 for 16B loads ------------------
__global__ __launch_bounds__(256) void pos_k(const float* __restrict__ pos,
                                             float4* __restrict__ posw) {
    int n = blockIdx.x * 256 + threadIdx.x;
    posw[n] = make_float4(pos[3*n], pos[3*n+1], pos[3*n+2], 0.f);
}

// ---------------- fused aggregate + node update (j-ownership) ----------------
// Phase 1 (per chunk of 16 edges, per 16-lane node group, zero barriers):
//   step A: lane e computes SH Y[16] for edge e once, stages to LDS (b128).
//   step B: lane j accumulates acc[u] += x[s_e][u] * Y_e[j]; s_e via __shfl.
// Lane j then holds agg[n][0:16][j] in registers = exactly phase-3's input:
// no transpose, no sT. Block=512 (32 groups) amortizes weight LDS -> 2 blk/CU.
#define GROUPS 32
#define BLK 512
#define YST 20                 // words per edge row (16B-aligned, bank-friendly)
#define GST (16*YST + 8)       // 328 words per group (8-word group stagger)

__global__ __launch_bounds__(512, 4) void fused_k(const float* __restrict__ x,
                                                  const float4* __restrict__ posw,
                                                  const int* __restrict__ row_ptr,
                                                  const int* __restrict__ edge_csr,
                                                  const float* __restrict__ Wpre,
                                                  const float* __restrict__ Wpost,
                                                  const float* __restrict__ Wsc,
                                                  float* __restrict__ out) {
    __shared__ float sPre[4*516];
    __shared__ float sPost[4*1028];
    __shared__ float sSc[512];
    __shared__ float sY[GROUPS * GST];   // 41984 B

    int t = threadIdx.x;
    for (int idx = t; idx < 2048; idx += BLK)
        sPre[(idx >> 9)*516 + (idx & 511)] = Wpre[idx];
    for (int idx = t; idx < 4096; idx += BLK)
        sPost[(idx >> 10)*1028 + (idx & 1023)] = Wpost[idx];
    sSc[t] = Wsc[t];

    int g = t >> 4;                  // node group 0..31
    int j = t & 15;                  // lane-in-group: edge slot (A) / output j (B,3)
    int n = blockIdx.x * GROUPS + g;
    int beg = row_ptr[n], end = row_ptr[n + 1];
    int cnt = end - beg;
    float4 rp = posw[n];
    float* yg = sY + g * GST;

    const float s3   = 1.7320508075688772f;
    const float s5   = 2.2360679774997896f;
    const float s15  = 3.8729833462074170f;
    const float s7   = 2.6457513110645907f;
    const float s105 = 10.246950765959598f;
    const float s35_8 = 2.0916500663351889f;
    const float s21_8 = 1.6201851746019651f;

    float acc[16];
#pragma unroll
    for (int u = 0; u < 16; ++u) acc[u] = 0.f;

    int nch = (cnt + 15) >> 4;
    for (int c = 0; c < nch; ++c) {
        int rem = cnt - (c << 4); rem = rem > 16 ? 16 : rem;

        // ---- step A: my edge's SH ----
        int k = (c << 4) + j;
        int ki = k < cnt ? k : cnt - 1;
        int sE = edge_csr[beg + ki];
        float4 sp = posw[sE];
        float vx = rp.x - sp.x, vy = rp.y - sp.y, vz = rp.z - sp.z;
        float n2 = vx*vx + vy*vy + vz*vz;
        float inv;
        if (n2 > 0.f) {
            inv = rsqrtf(n2);
            inv = inv * (1.5f - 0.5f * n2 * inv * inv);   // Newton: ~exact f32
        } else inv = 0.f;
        float X = vx*inv, Y = vy*inv, Z = vz*inv;
        float XX = X*X, YY = Y*Y, ZZ = Z*Z;

        float* yr = yg + j * YST;
        ((float4*)yr)[0] = make_float4(1.f, s3*X, s3*Y, s3*Z);
        ((float4*)yr)[1] = make_float4(s15*X*Y, s15*Y*Z,
                                       0.5f*s5*(3.f*ZZ - 1.f), s15*X*Z);
        ((float4*)yr)[2] = make_float4(0.5f*s15*(XX - YY),
                                       s35_8*Y*(3.f*XX - YY),
                                       s105*X*Y*Z,
                                       s21_8*Y*(5.f*ZZ - 1.f));
        ((float4*)yr)[3] = make_float4(0.5f*s7*Z*(5.f*ZZ - 3.f),
                                       s21_8*X*(5.f*ZZ - 1.f),
                                       0.5f*s105*Z*(XX - YY),
                                       s35_8*X*(XX - 3.f*YY));

        // ---- step B: accumulate my j-column over the chunk's edges ----
#pragma unroll 4
        for (int e = 0; e < rem; ++e) {
            int se = __shfl(sE, (t & 48) + e, 64);       // edge e's sender
            float y = yg[e * YST + j];
            const float4* xp = (const float4*)(x + (se << 4));
            float4 a0 = xp[0], a1 = xp[1], a2 = xp[2], a3 = xp[3];
            acc[0]  += a0.x * y;  acc[1]  += a0.y * y;
            acc[2]  += a0.z * y;  acc[3]  += a0.w * y;
            acc[4]  += a1.x * y;  acc[5]  += a1.y * y;
            acc[6]  += a1.z * y;  acc[7]  += a1.w * y;
            acc[8]  += a2.x * y;  acc[9]  += a2.y * y;
            acc[10] += a2.z * y;  acc[11] += a2.w * y;
            acc[12] += a3.x * y;  acc[13] += a3.y * y;
            acc[14] += a3.z * y;  acc[15] += a3.w * y;
        }
    }
    __syncthreads();   // weights staged (also separates sY use, though intra-wave)

    // ---- phase 3: per-(n,j) node update; input = acc registers ----
    int l, i, offl, deg;
    if (j == 0)      { l = 0; i = 0;     offl = 0;   deg = 1; }
    else if (j < 4)  { l = 1; i = j - 1; offl = 32;  deg = 3; }
    else if (j < 9)  { l = 2; i = j - 4; offl = 128; deg = 5; }
    else             { l = 3; i = j - 9; offl = 288; deg = 7; }

    const float c1 = 0.0078125f;            // (1/DENOM) * inv_in
    const float c2 = 0.17677669529663687f;  // 1/sqrt(32)

    float p[32];
#pragma unroll
    for (int v = 0; v < 32; ++v) p[v] = 0.f;
    const float* wp = sPre + l * 516;
#pragma unroll
    for (int uu = 0; uu < 16; ++uu) {
        float a = acc[uu];
        const float4* w4 = (const float4*)(wp + (uu << 5));
#pragma unroll
        for (int vq = 0; vq < 8; ++vq) {
            float4 w = w4[vq];
            p[4*vq+0] += a * w.x;
            p[4*vq+1] += a * w.y;
            p[4*vq+2] += a * w.z;
            p[4*vq+3] += a * w.w;
        }
    }
#pragma unroll
    for (int v = 0; v < 32; ++v) p[v] *= c1;

    if (j == 0) {
#pragma unroll
        for (int v = 0; v < 32; ++v) {
            float pv = p[v];
            p[v] = C_GELU_F * 0.5f * pv * (1.f + erff(pv * 0.7071067811865476f));
        }
    }

    float q[32];
#pragma unroll
    for (int w = 0; w < 32; ++w) q[w] = 0.f;
    const float* wq = sPost + l * 1028;
#pragma unroll
    for (int v = 0; v < 32; ++v) {
        float pv = p[v];
        const float4* w4 = (const float4*)(wq + (v << 5));
#pragma unroll
        for (int wd = 0; wd < 8; ++wd) {
            float4 w = w4[wd];
            q[4*wd+0] += pv * w.x;
            q[4*wd+1] += pv * w.y;
            q[4*wd+2] += pv * w.z;
            q[4*wd+3] += pv * w.w;
        }
    }
#pragma unroll
    for (int w = 0; w < 32; ++w) q[w] *= c2;

    if (j == 0) {   // shortcut: (x @ Wsc) * 1/4, only the 0e path
        const float* xp = x + (n << 4);
#pragma unroll
        for (int uu = 0; uu < 16; ++uu) {
            float xv = 0.25f * xp[uu];
            const float4* w4 = (const float4*)(sSc + (uu << 5));
#pragma unroll
            for (int wd = 0; wd < 8; ++wd) {
                float4 w = w4[wd];
                q[4*wd+0] += xv * w.x;
                q[4*wd+1] += xv * w.y;
                q[4*wd+2] += xv * w.z;
                q[4*wd+3] += xv * w.w;
            }
        }
    }

    float* op = out + (n << 9) + offl + i;
#pragma unroll
    for (int w = 0; w < 32; ++w) op[w * deg] = q[w];
}

extern "C" void kernel_launch(void* const* d_in, const int* in_sizes, int n_in,
                              void* d_out, int out_size, void* d_ws, size_t ws_size,
                              hipStream_t stream) {
    const float* x     = (const float*)d_in[0];
    const float* pos   = (const float*)d_in[1];
    const float* Wpre  = (const float*)d_in[2];
    const float* Wpost = (const float*)d_in[3];
    const float* Wsc   = (const float*)d_in[4];
    const int*   snd   = (const int*)d_in[5];
    const int*   rcv   = (const int*)d_in[6];
    float* out = (float*)d_out;

    char* ws = (char*)d_ws;
    int*      bin_cur   = (int*)(ws);                    // 1 KiB
    int*      bin_start = (int*)(ws + 1024);             // 1 KiB
    int*      row_ptr   = (int*)(ws + 2048);             // 128 KiB + 4
    float4*   posw      = (float4*)(ws + 0x30000);       // 512 KiB
    int*      edge_csr  = (int*)(ws + 0xB0000);          // 4 MiB
    unsigned* binbuf    = (unsigned*)(ws + 0x500000);    // 8 MiB

    hipMemsetAsync(bin_cur, 0, NBIN * sizeof(int), stream);
    bin_k<<<EN / TILE, 512, 0, stream>>>(snd, rcv, bin_cur, binbuf);
    scan_k<<<1, 256, 0, stream>>>(bin_cur, bin_start);
    csr_k<<<NBIN, 1024, 0, stream>>>(bin_cur, bin_start, binbuf, row_ptr, edge_csr);
    pos_k<<<NN / 256, 256, 0, stream>>>(pos, posw);
    fused_k<<<NN / GROUPS, BLK, 0, stream>>>(x, posw, row_ptr, edge_csr,
                                             Wpre, Wpost, Wsc, out);
}